// Round 2
// baseline (328.109 us; speedup 1.0000x reference)
//
#include <hip/hip_runtime.h>
#include <cstdint>

typedef __attribute__((ext_vector_type(8))) short short8;
typedef __attribute__((ext_vector_type(8))) unsigned short ushort8;
typedef __attribute__((ext_vector_type(4))) unsigned short ushort4v;
typedef __attribute__((ext_vector_type(2))) unsigned short ushort2v;
typedef __attribute__((ext_vector_type(4))) float f32x4;

constexpr int NB = 256, MC = 128, MP = 256;

__device__ __forceinline__ float b2f(unsigned short h) {
    return __uint_as_float(((unsigned)h) << 16);
}
__device__ __forceinline__ unsigned short f2b(float f) {
    unsigned u = __float_as_uint(f);
    u += 0x7fffu + ((u >> 16) & 1u);
    return (unsigned short)(u >> 16);
}

// elementwise f32 -> bf16 (vectorized, grid-stride)
__global__ __launch_bounds__(256)
void cvt_f32_bf16(const float* __restrict__ in, unsigned short* __restrict__ out, int n4) {
    int i = blockIdx.x * 256 + threadIdx.x;
    int stride = gridDim.x * 256;
    for (; i < n4; i += stride) {
        float4 v = ((const float4*)in)[i];
        ushort4v o;
        o.x = f2b(v.x); o.y = f2b(v.y); o.z = f2b(v.z); o.w = f2b(v.w);
        ((ushort4v*)out)[i] = o;
    }
}

// ---------------------------------------------------------------------------
// bf16 MFMA GEMM. C = A * B^T (modes 0,1,3) or A * B with B-rows gathered
// over k (mode 2). All accumulation fp32, outputs bf16.
// MODE 0 proj : Y[gr,gc] = dot + bias[gc]                (A rows clamped)
// MODE 1 score: S[bz,gr,gc] = mask ? dot/16 : -1e9       (A,B rows gathered)
// MODE 2 AV   : O[bz,gr,gc] = sum_k Attn[bz,gr,k] * V[bidx[bz,k],gc]
// MODE 3 gate : C[gr,gc] = C[gr,gc] * sigmoid(dot + bias[gc])   (in place,
//               block owns all 256 output cols of its rows -> race-free)
// Fragment convention: slot (g=lane>>4, e) <-> k = g*8+e for both A and B
// (bijective & consistent => correct dot). C/D: col=lane&15, row=g*4+reg.
// ---------------------------------------------------------------------------
template<int MODE>
__global__ __launch_bounds__(256)
void mfma_gemm(const unsigned short* __restrict__ A, const unsigned short* __restrict__ B,
               unsigned short* __restrict__ C, const float* __restrict__ bias,
               const int* __restrict__ aidx, const int* __restrict__ bidx,
               const int* __restrict__ rlen, const int* __restrict__ cln,
               int M, int N, int K)
{
    constexpr int BM = (MODE == 3) ? 64 : 128;
    constexpr int BN = (MODE == 3) ? 256 : 128;
    constexpr int RS = 40;  // padded LDS row stride (bf16): 80B, 16B-aligned, 2-way banks
    __shared__ unsigned short As[BM][RS];
    __shared__ unsigned short Bs[BN][RS];

    const int t = threadIdx.x;
    const int wid = t >> 6, l = t & 63, g = l >> 4, lr = l & 15;
    const int wr = (MODE == 3) ? 0 : (wid >> 1);
    const int wc = (MODE == 3) ? wid : (wid & 1);
    const int r0 = blockIdx.x * BM, c0 = blockIdx.y * BN;
    const int bz = blockIdx.z;

    f32x4 acc[4][4];
#pragma unroll
    for (int mi = 0; mi < 4; ++mi)
#pragma unroll
        for (int ni = 0; ni < 4; ++ni) acc[mi][ni] = (f32x4){0.f, 0.f, 0.f, 0.f};

    for (int k0 = 0; k0 < K; k0 += 32) {
        __syncthreads();
        // ---- stage A tile [BM][32] ----
        {
            int row = t >> 2, chunk = t & 3;
#pragma unroll
            for (int p = 0; p < BM / 64; ++p) {
                int r = p * 64 + row;
                const unsigned short* ap;
                if constexpr (MODE == 0) { int grr = r0 + r; if (grr >= M) grr = M - 1; ap = A + (size_t)grr * 256; }
                else if constexpr (MODE == 1) { ap = A + (size_t)aidx[bz * M + r0 + r] * 256; }
                else if constexpr (MODE == 2) { ap = A + ((size_t)bz * M + r0 + r) * K; }
                else { ap = A + (size_t)(r0 + r) * 256; }
                ushort8 v = *(const ushort8*)(ap + k0 + chunk * 8);
                *(ushort8*)&As[r][chunk * 8] = v;
            }
        }
        // ---- stage B tile ----
        if constexpr (MODE == 2) {
            // V rows gathered over k; transpose into Bs[col][k]
            int k = t >> 3;
            const unsigned short* bp = B + (size_t)bidx[bz * K + k0 + k] * 256;
#pragma unroll
            for (int p = 0; p < 2; ++p) {
                int chunk = p * 8 + (t & 7);
                ushort8 v = *(const ushort8*)(bp + c0 + chunk * 8);
#pragma unroll
                for (int e = 0; e < 8; ++e) Bs[chunk * 8 + e][k] = v[e];
            }
        } else {
            int col = t >> 2, chunk = t & 3;
#pragma unroll
            for (int p = 0; p < BN / 64; ++p) {
                int c = p * 64 + col;
                const unsigned short* bp;
                if constexpr (MODE == 1) bp = B + (size_t)bidx[bz * N + c0 + c] * 256;
                else                      bp = B + (size_t)(c0 + c) * 256;
                ushort8 v = *(const ushort8*)(bp + k0 + chunk * 8);
                *(ushort8*)&Bs[c][chunk * 8] = v;
            }
        }
        __syncthreads();

        short8 af[4], bfr[4];
#pragma unroll
        for (int mi = 0; mi < 4; ++mi)
            af[mi] = *(const short8*)&As[wr * 64 + mi * 16 + lr][g * 8];
#pragma unroll
        for (int ni = 0; ni < 4; ++ni)
            bfr[ni] = *(const short8*)&Bs[wc * 64 + ni * 16 + lr][g * 8];
#pragma unroll
        for (int mi = 0; mi < 4; ++mi)
#pragma unroll
            for (int ni = 0; ni < 4; ++ni)
                acc[mi][ni] = __builtin_amdgcn_mfma_f32_16x16x32_bf16(af[mi], bfr[ni], acc[mi][ni], 0, 0, 0);
    }

    // ---- epilogue ----
#pragma unroll
    for (int mi = 0; mi < 4; ++mi) {
#pragma unroll
        for (int ni = 0; ni < 4; ++ni) {
#pragma unroll
            for (int q = 0; q < 4; ++q) {
                int gr = r0 + wr * 64 + mi * 16 + g * 4 + q;
                int gc = c0 + wc * 64 + ni * 16 + lr;
                float v = acc[mi][ni][q];
                if constexpr (MODE == 0) {
                    if (gr < M) C[(size_t)gr * 256 + gc] = f2b(v + bias[gc]);
                } else if constexpr (MODE == 1) {
                    bool ok = (gr < rlen[bz]) && (gc < cln[bz]);
                    C[((size_t)bz * M + gr) * N + gc] = f2b(ok ? v * 0.0625f : -1e9f);
                } else if constexpr (MODE == 2) {
                    C[((size_t)bz * M + gr) * 256 + gc] = f2b(v);
                } else {
                    size_t o = (size_t)gr * 256 + gc;
                    float fused = b2f(C[o]);
                    float gate = 1.f / (1.f + expf(-(v + bias[gc])));
                    C[o] = f2b(fused * gate);
                }
            }
        }
    }
}

// ---------------------------------------------------------------------------
// In-place bf16 row softmax, one wave per row. imp (optional) <- 1/rowsum
// (== max over valid cols of softmaxed row; fully-masked rows -> 1/COLS).
// ---------------------------------------------------------------------------
template<int COLS>
__global__ __launch_bounds__(256)
void softmax_bf16(unsigned short* __restrict__ S, float* __restrict__ imp, int nrows)
{
    int wid = threadIdx.x >> 6, lane = threadIdx.x & 63;
    int row = blockIdx.x * 4 + wid;
    if (row >= nrows) return;
    unsigned short* p = S + (size_t)row * COLS;
    constexpr int PER = COLS / 64;
    float v[PER];
    if constexpr (PER == 4) {
        ushort4v tv = ((const ushort4v*)p)[lane];
        v[0] = b2f(tv.x); v[1] = b2f(tv.y); v[2] = b2f(tv.z); v[3] = b2f(tv.w);
    } else {
        ushort2v tv = ((const ushort2v*)p)[lane];
        v[0] = b2f(tv.x); v[1] = b2f(tv.y);
    }
    float m = v[0];
#pragma unroll
    for (int i = 1; i < PER; ++i) m = fmaxf(m, v[i]);
#pragma unroll
    for (int o = 32; o; o >>= 1) m = fmaxf(m, __shfl_xor(m, o));
    float s = 0.f;
#pragma unroll
    for (int i = 0; i < PER; ++i) { v[i] = expf(v[i] - m); s += v[i]; }
#pragma unroll
    for (int o = 32; o; o >>= 1) s += __shfl_xor(s, o);
    float inv = 1.f / s;
    if constexpr (PER == 4) {
        ushort4v o4;
        o4.x = f2b(v[0] * inv); o4.y = f2b(v[1] * inv);
        o4.z = f2b(v[2] * inv); o4.w = f2b(v[3] * inv);
        ((ushort4v*)p)[lane] = o4;
    } else {
        ushort2v o2;
        o2.x = f2b(v[0] * inv); o2.y = f2b(v[1] * inv);
        ((ushort2v*)p)[lane] = o2;
    }
    if (imp != nullptr && lane == 0) imp[row] = inv;
}

// imp_p[b,m] = max over valid n (< comp_len) of attn_cp[b,n,m]
__global__ __launch_bounds__(256)
void imp_p_max(const unsigned short* __restrict__ attn, const int* __restrict__ clens,
               float* __restrict__ imp_p)
{
    int b = blockIdx.x, m = threadIdx.x;
    int L = clens[b];
    const unsigned short* p = attn + (size_t)b * MC * MP + m;
    float mx = -1e30f;
    for (int n = 0; n < L; ++n) mx = fmaxf(mx, b2f(p[(size_t)n * MP]));
    imp_p[b * MP + m] = mx;
}

__device__ __forceinline__ float br_max(float v, float* red)
{
#pragma unroll
    for (int o = 32; o; o >>= 1) v = fmaxf(v, __shfl_xor(v, o));
    __syncthreads();
    if ((threadIdx.x & 63) == 0) red[threadIdx.x >> 6] = v;
    __syncthreads();
    return fmaxf(fmaxf(red[0], red[1]), fmaxf(red[2], red[3]));
}

__device__ __forceinline__ float br_sum(float v, float* red)
{
#pragma unroll
    for (int o = 32; o; o >>= 1) v += __shfl_xor(v, o);
    __syncthreads();
    if ((threadIdx.x & 63) == 0) red[threadIdx.x >> 6] = v;
    __syncthreads();
    return red[0] + red[1] + red[2] + red[3];
}

// Per-batch pooling softmaxes + weighted sums + logit.
__global__ __launch_bounds__(256)
void pool_kernel(const unsigned short* __restrict__ cg, const unsigned short* __restrict__ pg,
                 const float* __restrict__ imp_c, const float* __restrict__ imp_p,
                 const int* __restrict__ clens, const int* __restrict__ plens,
                 float* __restrict__ out)
{
    int b = blockIdx.x, t = threadIdx.x;
    __shared__ float w[256];
    __shared__ float red[4];
    int cl = clens[b], pl = plens[b];

    // w_c = softmax over MC of masked imp_c
    float x = (t < 128 && t < cl) ? imp_c[b * MC + t] : -1e30f;
    float mx = br_max(x, red);
    float e = (t < 128) ? expf(x - mx) : 0.f;
    float s = br_sum(e, red);
    if (t < 128) w[t] = e / s;
    __syncthreads();

    float hv = 0.f;
    for (int n = 0; n < MC; ++n)
        hv += w[n] * b2f(cg[((size_t)b * MC + n) * 256 + t]);
    __syncthreads();

    // w_p = softmax over MP of masked imp_p
    float x2 = (t < pl) ? imp_p[b * MP + t] : -1e30f;
    float mx2 = br_max(x2, red);
    float e2 = expf(x2 - mx2);
    float s2 = br_sum(e2, red);
    w[t] = e2 / s2;
    __syncthreads();

    float dv = 0.f;
    for (int m = 0; m < MP; ++m)
        dv += w[m] * b2f(pg[((size_t)b * MP + m) * 256 + t]);

    float logit = br_sum(hv * dv, red);
    if (t == 0) out[b] = 1.f / (1.f + expf(-logit));
}

// ---------------------------------------------------------------------------
extern "C" void kernel_launch(void* const* d_in, const int* in_sizes, int n_in,
                              void* d_out, int out_size, void* d_ws, size_t ws_size,
                              hipStream_t stream)
{
    const float* comp_emb = (const float*)d_in[0];
    const float* prot_emb = (const float*)d_in[1];
    const float* bq_c = (const float*)d_in[3];
    const float* bk_c = (const float*)d_in[5];
    const float* bv_c = (const float*)d_in[7];
    const float* bq_p = (const float*)d_in[9];
    const float* bk_p = (const float*)d_in[11];
    const float* bv_p = (const float*)d_in[13];
    const float* bg_c = (const float*)d_in[15];
    const float* bg_p = (const float*)d_in[17];
    const int* comp_idx  = (const int*)d_in[18];
    const int* prot_idx  = (const int*)d_in[19];
    const int* comp_lens = (const int*)d_in[20];
    const int* prot_lens = (const int*)d_in[21];
    float* out = (float*)d_out;

    const int N_C = in_sizes[0] / 256;
    const int N_P = in_sizes[1] / 256;
    const size_t NTc = (size_t)N_C * 256;
    const size_t NTp = (size_t)N_P * 256;
    const size_t NT  = (NTc > NTp) ? NTc : NTp;

    // ---- workspace layout (bf16 elements) — total ~120 MB ----
    unsigned short* comp_bf = (unsigned short*)d_ws;
    unsigned short* prot_bf = comp_bf + NTc;
    unsigned short* Wbf     = prot_bf + NTp;          // 8 x 65536
    unsigned short* tabA    = Wbf + 8 * 65536;        // phase A: cq | phase B: pq
    unsigned short* tabB    = tabA + NT;               // pk | ck
    unsigned short* tabC    = tabB + NT;               // pv | cv
    unsigned short* S       = tabC + NT;               // 8,388,608 (scores->attn, both dirs)
    unsigned short* cfused  = S + (size_t)NB * MC * MP;     // 8,388,608 (fused->gated in place)
    unsigned short* pfused  = cfused + (size_t)NB * MC * 256; // 16,777,216
    float* imp_c = (float*)(pfused + (size_t)NB * MP * 256);
    float* imp_p = imp_c + NB * MC;

    // ---- 0) conversions to bf16 ----
    {
        int n4 = (int)(NTc / 4);
        cvt_f32_bf16<<<dim3(2048), 256, 0, stream>>>(comp_emb, comp_bf, n4);
        cvt_f32_bf16<<<dim3(2048), 256, 0, stream>>>(prot_emb, prot_bf, (int)(NTp / 4));
        // weights at d_in[2,4,6,8,10,12,14,16]
        for (int j = 0; j < 8; ++j)
            cvt_f32_bf16<<<dim3(64), 256, 0, stream>>>((const float*)d_in[2 + 2 * j], Wbf + (size_t)j * 65536, 16384);
    }

    const int gpc = (N_C + 127) / 128, gpp = (N_P + 127) / 128;

    // ---- phase A: compound->protein attention ----
    mfma_gemm<0><<<dim3(gpc, 2, 1), 256, 0, stream>>>(comp_bf, Wbf + 0 * 65536, tabA, bq_c, nullptr, nullptr, nullptr, nullptr, N_C, 256, 256);
    mfma_gemm<0><<<dim3(gpp, 2, 1), 256, 0, stream>>>(prot_bf, Wbf + 4 * 65536, tabB, bk_p, nullptr, nullptr, nullptr, nullptr, N_P, 256, 256);
    mfma_gemm<0><<<dim3(gpp, 2, 1), 256, 0, stream>>>(prot_bf, Wbf + 5 * 65536, tabC, bv_p, nullptr, nullptr, nullptr, nullptr, N_P, 256, 256);

    mfma_gemm<1><<<dim3(1, 2, NB), 256, 0, stream>>>(tabA, tabB, S, nullptr, comp_idx, prot_idx, comp_lens, prot_lens, MC, MP, 256);
    softmax_bf16<MP><<<dim3((NB * MC) / 4), 256, 0, stream>>>(S, imp_c, NB * MC);
    imp_p_max<<<dim3(NB), 256, 0, stream>>>(S, comp_lens, imp_p);
    mfma_gemm<2><<<dim3(1, 2, NB), 256, 0, stream>>>(S, tabC, cfused, nullptr, nullptr, prot_idx, nullptr, nullptr, MC, 256, 256);
    mfma_gemm<3><<<dim3((NB * MC) / 64, 1, 1), 256, 0, stream>>>(cfused, Wbf + 6 * 65536, cfused, bg_c, nullptr, nullptr, nullptr, nullptr, NB * MC, 256, 256);

    // ---- phase B: protein->compound attention (reuses tabA/B/C and S) ----
    mfma_gemm<0><<<dim3(gpp, 2, 1), 256, 0, stream>>>(prot_bf, Wbf + 3 * 65536, tabA, bq_p, nullptr, nullptr, nullptr, nullptr, N_P, 256, 256);
    mfma_gemm<0><<<dim3(gpc, 2, 1), 256, 0, stream>>>(comp_bf, Wbf + 1 * 65536, tabB, bk_c, nullptr, nullptr, nullptr, nullptr, N_C, 256, 256);
    mfma_gemm<0><<<dim3(gpc, 2, 1), 256, 0, stream>>>(comp_bf, Wbf + 2 * 65536, tabC, bv_c, nullptr, nullptr, nullptr, nullptr, N_C, 256, 256);

    mfma_gemm<1><<<dim3(2, 1, NB), 256, 0, stream>>>(tabA, tabB, S, nullptr, prot_idx, comp_idx, prot_lens, comp_lens, MP, MC, 256);
    softmax_bf16<MC><<<dim3((NB * MP) / 4), 256, 0, stream>>>(S, nullptr, NB * MP);
    mfma_gemm<2><<<dim3(2, 2, NB), 256, 0, stream>>>(S, tabC, pfused, nullptr, nullptr, comp_idx, nullptr, nullptr, MP, 256, MC);
    mfma_gemm<3><<<dim3((NB * MP) / 64, 1, 1), 256, 0, stream>>>(pfused, Wbf + 7 * 65536, pfused, bg_p, nullptr, nullptr, nullptr, nullptr, NB * MP, 256, 256);

    // ---- pooling + logit ----
    pool_kernel<<<dim3(NB), 256, 0, stream>>>(cfused, pfused, imp_c, imp_p, comp_lens, prot_lens, out);
}

// Round 3
// 306.447 us; speedup vs baseline: 1.0707x; 1.0707x over previous
//
#include <hip/hip_runtime.h>
#include <cstdint>

typedef __attribute__((ext_vector_type(8))) short short8;
typedef __attribute__((ext_vector_type(8))) unsigned short ushort8;
typedef __attribute__((ext_vector_type(4))) unsigned short ushort4v;
typedef __attribute__((ext_vector_type(2))) unsigned short ushort2v;
typedef __attribute__((ext_vector_type(4))) float f32x4;

constexpr int NB = 256, MC = 128, MP = 256;

__device__ __forceinline__ float b2f(unsigned short h) { return __uint_as_float(((unsigned)h) << 16); }
__device__ __forceinline__ unsigned short f2b(float f) {
    unsigned u = __float_as_uint(f);
    u += 0x7fffu + ((u >> 16) & 1u);
    return (unsigned short)(u >> 16);
}

// async global->LDS, 16B per lane. LDS dest must be wave-uniform base + lane*16,
// which our linear index mapping guarantees (i = p*256 + wid*64 + lane).
__device__ __forceinline__ void gld_lds16(const unsigned short* g, unsigned short* l) {
    __builtin_amdgcn_global_load_lds((const __attribute__((address_space(1))) void*)g,
                                     (__attribute__((address_space(3))) void*)l, 16, 0, 0);
}

// elementwise f32 -> bf16
__global__ __launch_bounds__(256)
void cvt_f32_bf16(const float* __restrict__ in, unsigned short* __restrict__ out, int n4) {
    int i = blockIdx.x * 256 + threadIdx.x;
    int stride = gridDim.x * 256;
    for (; i < n4; i += stride) {
        float4 v = ((const float4*)in)[i];
        ushort4v o;
        o.x = f2b(v.x); o.y = f2b(v.y); o.z = f2b(v.z); o.w = f2b(v.w);
        ((ushort4v*)out)[i] = o;
    }
}

// ---------------------------------------------------------------------------
// bf16 MFMA GEMM, m97-style: BK=64 k-tiles, global_load_lds(16B) staging into
// linear LDS, XOR slot-swizzle applied on the GLOBAL source and on the
// fragment ds_read_b128 (both-sides-or-neither, rule #21).
// Element (row r, k) lives at LDS short-index r*64 + ((k>>3)^(r&7))*8 + (k&7).
// MODE 0 proj : Y = A.W^T + bias       (A rows clamped to M-1)
// MODE 1 score: S = mask ? A.B^T/16 : -1e9   (A,B rows gathered via idx)
// MODE 2 AV   : O = Attn . V[gather]   (V transposed into LDS at stage time)
// MODE 3 gate : C = C * sigmoid(C0.W^T + bias), in place; BM=64,BN=256 so a
//               block owns full output rows -> no inter-block race.
// ---------------------------------------------------------------------------
template<int MODE>
__global__ __launch_bounds__(256)
void mfma_gemm(const unsigned short* __restrict__ A, const unsigned short* __restrict__ B,
               unsigned short* __restrict__ C, const float* __restrict__ bias,
               const int* __restrict__ aidx, const int* __restrict__ bidx,
               const int* __restrict__ rlen, const int* __restrict__ cln,
               int M, int N, int K)
{
    constexpr int BM = (MODE == 3) ? 64 : 128;
    constexpr int BN = (MODE == 3) ? 256 : 128;
    __shared__ __align__(16) unsigned short As[BM * 64];
    __shared__ __align__(16) unsigned short Bs[BN * 64];

    const int t = threadIdx.x;
    const int wid = t >> 6, l = t & 63, g = l >> 4, lr = l & 15;
    const int wrb = (MODE == 3) ? 0 : (wid >> 1) * 64;
    const int wcb = (MODE == 3) ? wid * 64 : (wid & 1) * 64;
    const int r0 = blockIdx.x * BM, c0 = blockIdx.y * BN;
    const int bz = blockIdx.z;

    f32x4 acc[4][4];
#pragma unroll
    for (int mi = 0; mi < 4; ++mi)
#pragma unroll
        for (int ni = 0; ni < 4; ++ni) acc[mi][ni] = (f32x4){0.f, 0.f, 0.f, 0.f};

    for (int k0 = 0; k0 < K; k0 += 64) {
        __syncthreads();
        // ---- stage A [BM][64] ----
        {
            constexpr int CA = (BM * 8) / 256;
#pragma unroll
            for (int p = 0; p < CA; ++p) {
                int i = p * 256 + t;
                int r = i >> 3, s = i & 7;
                const unsigned short* ap;
                if constexpr (MODE == 0) { int gr = r0 + r; if (gr >= M) gr = M - 1; ap = A + (size_t)gr * 256; }
                else if constexpr (MODE == 1) { ap = A + (size_t)aidx[bz * M + r0 + r] * 256; }
                else if constexpr (MODE == 2) { ap = A + ((size_t)bz * M + r0 + r) * K; }
                else { ap = A + (size_t)(r0 + r) * 256; }
                gld_lds16(ap + k0 + ((s ^ (r & 7)) << 3), &As[(size_t)i * 8]);
            }
        }
        // ---- stage B ----
        if constexpr (MODE == 2) {
            // V rows gathered over k, transposed into Bs[c][k] (packed u32 pairs).
            int a = t & 31;              // k-pair: k = 2a, 2a+1
            int cb = (t >> 5) * 16;      // 16 cols per thread
            const unsigned short* q0 = B + (size_t)bidx[bz * K + k0 + 2 * a] * 256 + c0 + cb;
            const unsigned short* q1 = B + (size_t)bidx[bz * K + k0 + 2 * a + 1] * 256 + c0 + cb;
            int slot = a >> 2;           // (2a)>>3
            int kl = (2 * a) & 7;        // even
#pragma unroll
            for (int q = 0; q < 2; ++q) {
                ushort8 v0 = *(const ushort8*)(q0 + q * 8);
                ushort8 v1 = *(const ushort8*)(q1 + q * 8);
#pragma unroll
                for (int e = 0; e < 8; ++e) {
                    int c = cb + q * 8 + e;
                    unsigned pk = (unsigned)v0[e] | ((unsigned)v1[e] << 16);
                    *(unsigned*)&Bs[c * 64 + ((slot ^ (c & 7)) << 3) + kl] = pk;
                }
            }
        } else {
            constexpr int CB = (BN * 8) / 256;
#pragma unroll
            for (int p = 0; p < CB; ++p) {
                int i = p * 256 + t;
                int c = i >> 3, s = i & 7;
                const unsigned short* bp;
                if constexpr (MODE == 1) bp = B + (size_t)bidx[bz * N + c0 + c] * 256;
                else                      bp = B + (size_t)(c0 + c) * 256;
                gld_lds16(bp + k0 + ((s ^ (c & 7)) << 3), &Bs[(size_t)i * 8]);
            }
        }
        __syncthreads();

        // ---- compute: 2 x (8 ds_read_b128 + 16 MFMA) ----
#pragma unroll
        for (int kk = 0; kk < 2; ++kk) {
            short8 af[4], bfr[4];
#pragma unroll
            for (int mi = 0; mi < 4; ++mi) {
                int r = wrb + mi * 16 + lr;
                af[mi] = *(const short8*)&As[r * 64 + ((((kk << 2) | g) ^ (r & 7)) << 3)];
            }
#pragma unroll
            for (int ni = 0; ni < 4; ++ni) {
                int c = wcb + ni * 16 + lr;
                bfr[ni] = *(const short8*)&Bs[c * 64 + ((((kk << 2) | g) ^ (c & 7)) << 3)];
            }
#pragma unroll
            for (int mi = 0; mi < 4; ++mi)
#pragma unroll
                for (int ni = 0; ni < 4; ++ni)
                    acc[mi][ni] = __builtin_amdgcn_mfma_f32_16x16x32_bf16(af[mi], bfr[ni], acc[mi][ni], 0, 0, 0);
        }
    }

    // ---- epilogue ----
#pragma unroll
    for (int mi = 0; mi < 4; ++mi) {
#pragma unroll
        for (int ni = 0; ni < 4; ++ni) {
#pragma unroll
            for (int q = 0; q < 4; ++q) {
                int gr = r0 + wrb + mi * 16 + g * 4 + q;
                int gc = c0 + wcb + ni * 16 + lr;
                float v = acc[mi][ni][q];
                if constexpr (MODE == 0) {
                    if (gr < M) C[(size_t)gr * 256 + gc] = f2b(v + bias[gc]);
                } else if constexpr (MODE == 1) {
                    bool ok = (gr < rlen[bz]) && (gc < cln[bz]);
                    C[((size_t)bz * M + gr) * N + gc] = f2b(ok ? v * 0.0625f : -1e9f);
                } else if constexpr (MODE == 2) {
                    C[((size_t)bz * M + gr) * 256 + gc] = f2b(v);
                } else {
                    size_t o = (size_t)gr * 256 + gc;
                    float fused = b2f(C[o]);
                    float gate = 1.f / (1.f + expf(-(v + bias[gc])));
                    C[o] = f2b(fused * gate);
                }
            }
        }
    }
}

// ---------------------------------------------------------------------------
// In-place bf16 row softmax, one wave per row; imp <- 1/rowsum (== max over
// valid cols of softmaxed row; fully-masked rows -> uniform, also matches).
// ---------------------------------------------------------------------------
template<int COLS>
__global__ __launch_bounds__(256)
void softmax_bf16(unsigned short* __restrict__ S, float* __restrict__ imp, int nrows)
{
    int wid = threadIdx.x >> 6, lane = threadIdx.x & 63;
    int row = blockIdx.x * 4 + wid;
    if (row >= nrows) return;
    unsigned short* p = S + (size_t)row * COLS;
    constexpr int PER = COLS / 64;
    float v[PER];
    if constexpr (PER == 4) {
        ushort4v tv = ((const ushort4v*)p)[lane];
        v[0] = b2f(tv.x); v[1] = b2f(tv.y); v[2] = b2f(tv.z); v[3] = b2f(tv.w);
    } else {
        ushort2v tv = ((const ushort2v*)p)[lane];
        v[0] = b2f(tv.x); v[1] = b2f(tv.y);
    }
    float m = v[0];
#pragma unroll
    for (int i = 1; i < PER; ++i) m = fmaxf(m, v[i]);
#pragma unroll
    for (int o = 32; o; o >>= 1) m = fmaxf(m, __shfl_xor(m, o));
    float s = 0.f;
#pragma unroll
    for (int i = 0; i < PER; ++i) { v[i] = expf(v[i] - m); s += v[i]; }
#pragma unroll
    for (int o = 32; o; o >>= 1) s += __shfl_xor(s, o);
    float inv = 1.f / s;
    if constexpr (PER == 4) {
        ushort4v o4;
        o4.x = f2b(v[0] * inv); o4.y = f2b(v[1] * inv);
        o4.z = f2b(v[2] * inv); o4.w = f2b(v[3] * inv);
        ((ushort4v*)p)[lane] = o4;
    } else {
        ushort2v o2;
        o2.x = f2b(v[0] * inv); o2.y = f2b(v[1] * inv);
        ((ushort2v*)p)[lane] = o2;
    }
    if (imp != nullptr && lane == 0) imp[row] = inv;
}

__global__ __launch_bounds__(256)
void imp_p_max(const unsigned short* __restrict__ attn, const int* __restrict__ clens,
               float* __restrict__ imp_p)
{
    int b = blockIdx.x, m = threadIdx.x;
    int L = clens[b];
    const unsigned short* p = attn + (size_t)b * MC * MP + m;
    float mx = -1e30f;
    for (int n = 0; n < L; ++n) mx = fmaxf(mx, b2f(p[(size_t)n * MP]));
    imp_p[b * MP + m] = mx;
}

__device__ __forceinline__ float br_max(float v, float* red)
{
#pragma unroll
    for (int o = 32; o; o >>= 1) v = fmaxf(v, __shfl_xor(v, o));
    __syncthreads();
    if ((threadIdx.x & 63) == 0) red[threadIdx.x >> 6] = v;
    __syncthreads();
    return fmaxf(fmaxf(red[0], red[1]), fmaxf(red[2], red[3]));
}

__device__ __forceinline__ float br_sum(float v, float* red)
{
#pragma unroll
    for (int o = 32; o; o >>= 1) v += __shfl_xor(v, o);
    __syncthreads();
    if ((threadIdx.x & 63) == 0) red[threadIdx.x >> 6] = v;
    __syncthreads();
    return red[0] + red[1] + red[2] + red[3];
}

__global__ __launch_bounds__(256)
void pool_kernel(const unsigned short* __restrict__ cg, const unsigned short* __restrict__ pg,
                 const float* __restrict__ imp_c, const float* __restrict__ imp_p,
                 const int* __restrict__ clens, const int* __restrict__ plens,
                 float* __restrict__ out)
{
    int b = blockIdx.x, t = threadIdx.x;
    __shared__ float w[256];
    __shared__ float red[4];
    int cl = clens[b], pl = plens[b];

    float x = (t < 128 && t < cl) ? imp_c[b * MC + t] : -1e30f;
    float mx = br_max(x, red);
    float e = (t < 128) ? expf(x - mx) : 0.f;
    float s = br_sum(e, red);
    if (t < 128) w[t] = e / s;
    __syncthreads();

    float hv = 0.f;
    for (int n = 0; n < MC; ++n)
        hv += w[n] * b2f(cg[((size_t)b * MC + n) * 256 + t]);
    __syncthreads();

    float x2 = (t < pl) ? imp_p[b * MP + t] : -1e30f;
    float mx2 = br_max(x2, red);
    float e2 = expf(x2 - mx2);
    float s2 = br_sum(e2, red);
    w[t] = e2 / s2;
    __syncthreads();

    float dv = 0.f;
    for (int m = 0; m < MP; ++m)
        dv += w[m] * b2f(pg[((size_t)b * MP + m) * 256 + t]);

    float logit = br_sum(hv * dv, red);
    if (t == 0) out[b] = 1.f / (1.f + expf(-logit));
}

// ---------------------------------------------------------------------------
extern "C" void kernel_launch(void* const* d_in, const int* in_sizes, int n_in,
                              void* d_out, int out_size, void* d_ws, size_t ws_size,
                              hipStream_t stream)
{
    const float* comp_emb = (const float*)d_in[0];
    const float* prot_emb = (const float*)d_in[1];
    const float* bq_c = (const float*)d_in[3];
    const float* bk_c = (const float*)d_in[5];
    const float* bv_c = (const float*)d_in[7];
    const float* bq_p = (const float*)d_in[9];
    const float* bk_p = (const float*)d_in[11];
    const float* bv_p = (const float*)d_in[13];
    const float* bg_c = (const float*)d_in[15];
    const float* bg_p = (const float*)d_in[17];
    const int* comp_idx  = (const int*)d_in[18];
    const int* prot_idx  = (const int*)d_in[19];
    const int* comp_lens = (const int*)d_in[20];
    const int* prot_lens = (const int*)d_in[21];
    float* out = (float*)d_out;

    const int N_C = in_sizes[0] / 256;
    const int N_P = in_sizes[1] / 256;
    const size_t NTc = (size_t)N_C * 256;
    const size_t NTp = (size_t)N_P * 256;
    const size_t NT  = (NTc > NTp) ? NTc : NTp;

    // ---- workspace layout (bf16 elements), ~130 MB (proven to fit) ----
    unsigned short* comp_bf = (unsigned short*)d_ws;
    unsigned short* prot_bf = comp_bf + NTc;
    unsigned short* Wbf     = prot_bf + NTp;          // 8 x 65536
    unsigned short* tabA    = Wbf + 8 * 65536;        // phase A: cq | phase B: pq
    unsigned short* tabB    = tabA + NT;              // pk | ck
    unsigned short* tabC    = tabB + NT;              // pv | cv
    unsigned short* S       = tabC + NT;              // scores->attn (both dirs)
    unsigned short* cfused  = S + (size_t)NB * MC * MP;
    unsigned short* pfused  = cfused + (size_t)NB * MC * 256;
    float* imp_c = (float*)(pfused + (size_t)NB * MP * 256);
    float* imp_p = imp_c + NB * MC;

    // ---- 0) conversions to bf16 ----
    cvt_f32_bf16<<<dim3(2048), 256, 0, stream>>>(comp_emb, comp_bf, (int)(NTc / 4));
    cvt_f32_bf16<<<dim3(2048), 256, 0, stream>>>(prot_emb, prot_bf, (int)(NTp / 4));
    for (int j = 0; j < 8; ++j)
        cvt_f32_bf16<<<dim3(64), 256, 0, stream>>>((const float*)d_in[2 + 2 * j], Wbf + (size_t)j * 65536, 16384);

    const int gpc = (N_C + 127) / 128, gpp = (N_P + 127) / 128;

    // ---- phase A: compound->protein ----
    mfma_gemm<0><<<dim3(gpc, 2, 1), 256, 0, stream>>>(comp_bf, Wbf + 0 * 65536, tabA, bq_c, nullptr, nullptr, nullptr, nullptr, N_C, 256, 256);
    mfma_gemm<0><<<dim3(gpp, 2, 1), 256, 0, stream>>>(prot_bf, Wbf + 4 * 65536, tabB, bk_p, nullptr, nullptr, nullptr, nullptr, N_P, 256, 256);
    mfma_gemm<0><<<dim3(gpp, 2, 1), 256, 0, stream>>>(prot_bf, Wbf + 5 * 65536, tabC, bv_p, nullptr, nullptr, nullptr, nullptr, N_P, 256, 256);

    mfma_gemm<1><<<dim3(1, 2, NB), 256, 0, stream>>>(tabA, tabB, S, nullptr, comp_idx, prot_idx, comp_lens, prot_lens, MC, MP, 256);
    softmax_bf16<MP><<<dim3((NB * MC) / 4), 256, 0, stream>>>(S, imp_c, NB * MC);
    imp_p_max<<<dim3(NB), 256, 0, stream>>>(S, comp_lens, imp_p);
    mfma_gemm<2><<<dim3(1, 2, NB), 256, 0, stream>>>(S, tabC, cfused, nullptr, nullptr, prot_idx, nullptr, nullptr, MC, 256, 256);
    mfma_gemm<3><<<dim3((NB * MC) / 64, 1, 1), 256, 0, stream>>>(cfused, Wbf + 6 * 65536, cfused, bg_c, nullptr, nullptr, nullptr, nullptr, NB * MC, 256, 256);

    // ---- phase B: protein->compound ----
    mfma_gemm<0><<<dim3(gpp, 2, 1), 256, 0, stream>>>(prot_bf, Wbf + 3 * 65536, tabA, bq_p, nullptr, nullptr, nullptr, nullptr, N_P, 256, 256);
    mfma_gemm<0><<<dim3(gpc, 2, 1), 256, 0, stream>>>(comp_bf, Wbf + 1 * 65536, tabB, bk_c, nullptr, nullptr, nullptr, nullptr, N_C, 256, 256);
    mfma_gemm<0><<<dim3(gpc, 2, 1), 256, 0, stream>>>(comp_bf, Wbf + 2 * 65536, tabC, bv_c, nullptr, nullptr, nullptr, nullptr, N_C, 256, 256);

    mfma_gemm<1><<<dim3(2, 1, NB), 256, 0, stream>>>(tabA, tabB, S, nullptr, prot_idx, comp_idx, prot_lens, comp_lens, MP, MC, 256);
    softmax_bf16<MC><<<dim3((NB * MP) / 4), 256, 0, stream>>>(S, nullptr, NB * MP);
    mfma_gemm<2><<<dim3(2, 2, NB), 256, 0, stream>>>(S, tabC, pfused, nullptr, nullptr, comp_idx, nullptr, nullptr, MP, 256, MC);
    mfma_gemm<3><<<dim3((NB * MP) / 64, 1, 1), 256, 0, stream>>>(pfused, Wbf + 7 * 65536, pfused, bg_p, nullptr, nullptr, nullptr, nullptr, NB * MP, 256, 256);

    // ---- pooling + logit ----
    pool_kernel<<<dim3(NB), 256, 0, stream>>>(cfused, pfused, imp_c, imp_p, comp_lens, prot_lens, out);
}

// Round 4
// 265.915 us; speedup vs baseline: 1.2339x; 1.1524x over previous
//
#include <hip/hip_runtime.h>
#include <cstdint>

typedef __attribute__((ext_vector_type(8))) short short8;
typedef __attribute__((ext_vector_type(8))) unsigned short ushort8;
typedef __attribute__((ext_vector_type(4))) unsigned short ushort4v;
typedef __attribute__((ext_vector_type(2))) unsigned short ushort2v;
typedef __attribute__((ext_vector_type(4))) float f32x4;

constexpr int NB = 256, MC = 128, MP = 256;
constexpr float L2E = 1.442695041f;

__device__ __forceinline__ float b2f(unsigned short h) { return __uint_as_float(((unsigned)h) << 16); }
__device__ __forceinline__ unsigned short f2b(float f) {
    unsigned u = __float_as_uint(f);
    u += 0x7fffu + ((u >> 16) & 1u);
    return (unsigned short)(u >> 16);
}
// sigmoid via single v_exp_f32 + v_rcp_f32 (bf16-accuracy ample)
__device__ __forceinline__ float sigmoid_f(float x) {
    return __builtin_amdgcn_rcpf(1.f + exp2f(-L2E * x));
}

// async global->LDS, 16B/lane; LDS dest is wave-uniform base + lane*16.
__device__ __forceinline__ void gld_lds16(const unsigned short* g, unsigned short* l) {
    __builtin_amdgcn_global_load_lds((const __attribute__((address_space(1))) void*)g,
                                     (__attribute__((address_space(3))) void*)l, 16, 0, 0);
}

__global__ __launch_bounds__(256)
void cvt_f32_bf16(const float* __restrict__ in, unsigned short* __restrict__ out, int n4) {
    int i = blockIdx.x * 256 + threadIdx.x;
    int stride = gridDim.x * 256;
    for (; i < n4; i += stride) {
        float4 v = ((const float4*)in)[i];
        ushort4v o;
        o.x = f2b(v.x); o.y = f2b(v.y); o.z = f2b(v.z); o.w = f2b(v.w);
        ((ushort4v*)out)[i] = o;
    }
}

// All 8 weight matrices -> one [2048][256] bf16 Wcat + bias_cat[2048] (f32).
// Row-block order: q_c,k_c,v_c,g_c,q_p,k_p,v_p,g_p.
__global__ __launch_bounds__(256)
void cvt_weights8(const float* w0, const float* w1, const float* w2, const float* w3,
                  const float* w4, const float* w5, const float* w6, const float* w7,
                  const float* b0, const float* b1, const float* b2, const float* b3,
                  const float* b4, const float* b5, const float* b6, const float* b7,
                  unsigned short* __restrict__ Wcat, float* __restrict__ bias_cat)
{
    const float* wsel[8] = {w0, w1, w2, w3, w4, w5, w6, w7};
    const float* bsel[8] = {b0, b1, b2, b3, b4, b5, b6, b7};
    int j = blockIdx.y;
    int i = blockIdx.x * 256 + threadIdx.x;   // float4 index within 65536-elem weight
    float4 v = ((const float4*)wsel[j])[i];
    ushort4v o;
    o.x = f2b(v.x); o.y = f2b(v.y); o.z = f2b(v.z); o.w = f2b(v.w);
    ((ushort4v*)(Wcat + (size_t)j * 65536))[i] = o;
    if (blockIdx.x == 0) bias_cat[j * 256 + threadIdx.x] = bsel[j][threadIdx.x];
}

// ---------------------------------------------------------------------------
// bf16 MFMA GEMM, double-buffered BK=32 pipeline (T3-minimal 2-phase):
// prologue stage(buf0); loop { stage(next) ; ds_read+MFMA(cur) ; barrier }.
// Next-tile global_load_lds stays in flight UNDER the MFMA phase; the barrier
// at loop bottom drains it (compiler emits vmcnt(0) there).
// LDS: element (row r, k) at short-index r*32 + ((k>>3 ^ (r&3))<<3) + (k&7);
// staged linearly from inverse-swizzled GLOBAL source (both-sides rule #21).
// Fragment convention k = (lane>>4)*8+e for A and B (consistent => correct).
// MODE 0 proj : Y[gr,gc] = dot + bias[gc], C stride N (supports fused N=512)
// MODE 1 score: S = mask ? dot/16 : -1e9    (A,B rows gathered; B stride bstr)
// MODE 2 AV   : O = Attn . V[gather]        (V transposed at stage; bstr)
// MODE 3 gate : C = C * sigmoid(dot + bias), in place (block owns full rows)
// ---------------------------------------------------------------------------
template<int MODE>
__global__ __launch_bounds__(256, 4)
void mfma_gemm(const unsigned short* __restrict__ A, const unsigned short* __restrict__ B,
               unsigned short* __restrict__ C, const float* __restrict__ bias,
               const int* __restrict__ aidx, const int* __restrict__ bidx,
               const int* __restrict__ rlen, const int* __restrict__ cln,
               int M, int N, int K, int bstr)
{
    constexpr int BM = (MODE == 3) ? 64 : 128;
    constexpr int BN = (MODE == 3) ? 256 : 128;
    __shared__ __align__(16) unsigned short As[2][BM * 32];
    __shared__ __align__(16) unsigned short Bs[2][BN * 32];

    const int t = threadIdx.x;
    const int wid = t >> 6, l = t & 63, g = l >> 4, lr = l & 15;
    const int wrb = (MODE == 3) ? 0 : (wid >> 1) * 64;
    const int wcb = (MODE == 3) ? wid * 64 : (wid & 1) * 64;
    const int r0 = blockIdx.x * BM, c0 = blockIdx.y * BN;
    const int bz = blockIdx.z;

    f32x4 acc[4][4];
#pragma unroll
    for (int mi = 0; mi < 4; ++mi)
#pragma unroll
        for (int ni = 0; ni < 4; ++ni) acc[mi][ni] = (f32x4){0.f, 0.f, 0.f, 0.f};

    auto stage = [&](int buf, int k0) {
        // ---- A tile [BM][32] via global_load_lds ----
        constexpr int CA = (BM * 4) / 256;
#pragma unroll
        for (int p = 0; p < CA; ++p) {
            int i = p * 256 + t;
            int r = i >> 2, s = i & 3;
            const unsigned short* ap;
            if constexpr (MODE == 0) { int gr = r0 + r; if (gr >= M) gr = M - 1; ap = A + (size_t)gr * 256; }
            else if constexpr (MODE == 1) { ap = A + (size_t)aidx[bz * M + r0 + r] * 256; }
            else if constexpr (MODE == 2) { ap = A + ((size_t)bz * M + r0 + r) * K; }
            else { ap = A + (size_t)(r0 + r) * 256; }
            gld_lds16(ap + k0 + ((s ^ (r & 3)) << 3), &As[buf][i * 8]);
        }
        // ---- B tile ----
        if constexpr (MODE == 2) {
            // gather 32 V rows, transpose into Bs[c][k] as packed k-pairs
            int a = t & 15, cb = (t >> 4) * 8;
            const unsigned short* q0 = B + (size_t)bidx[bz * K + k0 + 2 * a] * bstr + c0 + cb;
            const unsigned short* q1 = B + (size_t)bidx[bz * K + k0 + 2 * a + 1] * bstr + c0 + cb;
            ushort8 v0 = *(const ushort8*)q0;
            ushort8 v1 = *(const ushort8*)q1;
            int gg = a >> 2, kl = (2 * a) & 7;
#pragma unroll
            for (int e = 0; e < 8; ++e) {
                int c = cb + e;
                *(unsigned*)&Bs[buf][c * 32 + ((gg ^ (c & 3)) << 3) + kl] =
                    (unsigned)(unsigned short)v0[e] | ((unsigned)(unsigned short)v1[e] << 16);
            }
        } else {
            constexpr int CB = (BN * 4) / 256;
#pragma unroll
            for (int p = 0; p < CB; ++p) {
                int i = p * 256 + t;
                int c = i >> 2, s = i & 3;
                const unsigned short* bp;
                if constexpr (MODE == 1) bp = B + (size_t)bidx[bz * N + c0 + c] * bstr;
                else                      bp = B + (size_t)(c0 + c) * bstr;
                gld_lds16(bp + k0 + ((s ^ (c & 3)) << 3), &Bs[buf][i * 8]);
            }
        }
    };

    stage(0, 0);
    __syncthreads();
    const int NT_ = K >> 5;
    for (int it = 0; it < NT_; ++it) {
        const int cur = it & 1;
        if (it + 1 < NT_) stage(cur ^ 1, (it + 1) << 5);   // loads fly under MFMA
        short8 af[4], bfr[4];
#pragma unroll
        for (int mi = 0; mi < 4; ++mi) {
            int r = wrb + mi * 16 + lr;
            af[mi] = *(const short8*)&As[cur][r * 32 + ((g ^ (r & 3)) << 3)];
        }
#pragma unroll
        for (int ni = 0; ni < 4; ++ni) {
            int c = wcb + ni * 16 + lr;
            bfr[ni] = *(const short8*)&Bs[cur][c * 32 + ((g ^ (c & 3)) << 3)];
        }
#pragma unroll
        for (int mi = 0; mi < 4; ++mi)
#pragma unroll
            for (int ni = 0; ni < 4; ++ni)
                acc[mi][ni] = __builtin_amdgcn_mfma_f32_16x16x32_bf16(af[mi], bfr[ni], acc[mi][ni], 0, 0, 0);
        if (it + 1 < NT_) __syncthreads();
    }

    // ---- epilogue ----
#pragma unroll
    for (int mi = 0; mi < 4; ++mi) {
#pragma unroll
        for (int ni = 0; ni < 4; ++ni) {
#pragma unroll
            for (int q = 0; q < 4; ++q) {
                int gr = r0 + wrb + mi * 16 + g * 4 + q;
                int gc = c0 + wcb + ni * 16 + lr;
                float v = acc[mi][ni][q];
                if constexpr (MODE == 0) {
                    if (gr < M) C[(size_t)gr * N + gc] = f2b(v + bias[gc]);
                } else if constexpr (MODE == 1) {
                    bool ok = (gr < rlen[bz]) && (gc < cln[bz]);
                    C[((size_t)bz * M + gr) * N + gc] = f2b(ok ? v * 0.0625f : -1e9f);
                } else if constexpr (MODE == 2) {
                    C[((size_t)bz * M + gr) * 256 + gc] = f2b(v);
                } else {
                    size_t o = (size_t)gr * 256 + gc;
                    C[o] = f2b(b2f(C[o]) * sigmoid_f(v + bias[gc]));
                }
            }
        }
    }
}

// ---------------------------------------------------------------------------
// In-place bf16 row softmax, one wave per row; imp <- 1/rowsum (== max over
// valid cols of softmaxed row; fully-masked rows -> uniform, also matches).
// exp via exp2((x-m)*log2e) — identical math, single v_exp_f32.
// ---------------------------------------------------------------------------
template<int COLS>
__global__ __launch_bounds__(256)
void softmax_bf16(unsigned short* __restrict__ S, float* __restrict__ imp, int nrows)
{
    int wid = threadIdx.x >> 6, lane = threadIdx.x & 63;
    int row = blockIdx.x * 4 + wid;
    if (row >= nrows) return;
    unsigned short* p = S + (size_t)row * COLS;
    constexpr int PER = COLS / 64;
    float v[PER];
    if constexpr (PER == 4) {
        ushort4v tv = ((const ushort4v*)p)[lane];
        v[0] = b2f(tv.x); v[1] = b2f(tv.y); v[2] = b2f(tv.z); v[3] = b2f(tv.w);
    } else {
        ushort2v tv = ((const ushort2v*)p)[lane];
        v[0] = b2f(tv.x); v[1] = b2f(tv.y);
    }
    float m = v[0];
#pragma unroll
    for (int i = 1; i < PER; ++i) m = fmaxf(m, v[i]);
#pragma unroll
    for (int o = 32; o; o >>= 1) m = fmaxf(m, __shfl_xor(m, o));
    float s = 0.f;
#pragma unroll
    for (int i = 0; i < PER; ++i) { v[i] = exp2f((v[i] - m) * L2E); s += v[i]; }
#pragma unroll
    for (int o = 32; o; o >>= 1) s += __shfl_xor(s, o);
    float inv = 1.f / s;
    if constexpr (PER == 4) {
        ushort4v o4;
        o4.x = f2b(v[0] * inv); o4.y = f2b(v[1] * inv);
        o4.z = f2b(v[2] * inv); o4.w = f2b(v[3] * inv);
        ((ushort4v*)p)[lane] = o4;
    } else {
        ushort2v o2;
        o2.x = f2b(v[0] * inv); o2.y = f2b(v[1] * inv);
        ((ushort2v*)p)[lane] = o2;
    }
    if (imp != nullptr && lane == 0) imp[row] = inv;
}

__global__ __launch_bounds__(256)
void imp_p_max(const unsigned short* __restrict__ attn, const int* __restrict__ clens,
               float* __restrict__ imp_p)
{
    int b = blockIdx.x, m = threadIdx.x;
    int L = clens[b];
    const unsigned short* p = attn + (size_t)b * MC * MP + m;
    float mx = -1e30f;
    for (int n = 0; n < L; ++n) mx = fmaxf(mx, b2f(p[(size_t)n * MP]));
    imp_p[b * MP + m] = mx;
}

__device__ __forceinline__ float br_max(float v, float* red)
{
#pragma unroll
    for (int o = 32; o; o >>= 1) v = fmaxf(v, __shfl_xor(v, o));
    __syncthreads();
    if ((threadIdx.x & 63) == 0) red[threadIdx.x >> 6] = v;
    __syncthreads();
    return fmaxf(fmaxf(red[0], red[1]), fmaxf(red[2], red[3]));
}

__device__ __forceinline__ float br_sum(float v, float* red)
{
#pragma unroll
    for (int o = 32; o; o >>= 1) v += __shfl_xor(v, o);
    __syncthreads();
    if ((threadIdx.x & 63) == 0) red[threadIdx.x >> 6] = v;
    __syncthreads();
    return red[0] + red[1] + red[2] + red[3];
}

__global__ __launch_bounds__(256)
void pool_kernel(const unsigned short* __restrict__ cg, const unsigned short* __restrict__ pg,
                 const float* __restrict__ imp_c, const float* __restrict__ imp_p,
                 const int* __restrict__ clens, const int* __restrict__ plens,
                 float* __restrict__ out)
{
    int b = blockIdx.x, t = threadIdx.x;
    __shared__ float w[256];
    __shared__ float red[4];
    int cl = clens[b], pl = plens[b];

    float x = (t < 128 && t < cl) ? imp_c[b * MC + t] : -1e30f;
    float mx = br_max(x, red);
    float e = (t < 128) ? exp2f((x - mx) * L2E) : 0.f;
    float s = br_sum(e, red);
    if (t < 128) w[t] = e / s;
    __syncthreads();

    float hv = 0.f;
    for (int n = 0; n < MC; ++n)
        hv += w[n] * b2f(cg[((size_t)b * MC + n) * 256 + t]);
    __syncthreads();

    float x2 = (t < pl) ? imp_p[b * MP + t] : -1e30f;
    float mx2 = br_max(x2, red);
    float e2 = exp2f((x2 - mx2) * L2E);
    float s2 = br_sum(e2, red);
    w[t] = e2 / s2;
    __syncthreads();

    float dv = 0.f;
    for (int m = 0; m < MP; ++m)
        dv += w[m] * b2f(pg[((size_t)b * MP + m) * 256 + t]);

    float logit = br_sum(hv * dv, red);
    if (t == 0) out[b] = 1.f / (1.f + expf(-logit));
}

// ---------------------------------------------------------------------------
extern "C" void kernel_launch(void* const* d_in, const int* in_sizes, int n_in,
                              void* d_out, int out_size, void* d_ws, size_t ws_size,
                              hipStream_t stream)
{
    const float* comp_emb = (const float*)d_in[0];
    const float* prot_emb = (const float*)d_in[1];
    const int* comp_idx  = (const int*)d_in[18];
    const int* prot_idx  = (const int*)d_in[19];
    const int* comp_lens = (const int*)d_in[20];
    const int* prot_lens = (const int*)d_in[21];
    float* out = (float*)d_out;

    const int N_C = in_sizes[0] / 256;
    const int N_P = in_sizes[1] / 256;
    const size_t NTc = (size_t)N_C * 256;
    const size_t NTp = (size_t)N_P * 256;
    const int NR = (N_C > N_P) ? N_C : N_P;

    // ---- workspace layout (bf16 elements), ~120 MB ----
    unsigned short* comp_bf = (unsigned short*)d_ws;
    unsigned short* prot_bf = comp_bf + NTc;
    unsigned short* Wcat    = prot_bf + NTp;                 // [2048][256]
    float* bias_cat         = (float*)(Wcat + 2048 * 256);   // [2048]
    unsigned short* tabA    = (unsigned short*)(bias_cat + 2048);  // [NR][256] (cq | pq)
    unsigned short* tabKV   = tabA + (size_t)NR * 256;       // [NR][512]  (k|v fused)
    unsigned short* S       = tabKV + (size_t)NR * 512;      // scores->attn
    unsigned short* cfused  = S + (size_t)NB * MC * MP;
    unsigned short* pfused  = cfused + (size_t)NB * MC * 256;
    float* imp_c = (float*)(pfused + (size_t)NB * MP * 256);
    float* imp_p = imp_c + NB * MC;

    // ---- conversions ----
    cvt_f32_bf16<<<dim3(2048), 256, 0, stream>>>(comp_emb, comp_bf, (int)(NTc / 4));
    cvt_f32_bf16<<<dim3(2048), 256, 0, stream>>>(prot_emb, prot_bf, (int)(NTp / 4));
    cvt_weights8<<<dim3(64, 8), 256, 0, stream>>>(
        (const float*)d_in[2], (const float*)d_in[4], (const float*)d_in[6], (const float*)d_in[14],
        (const float*)d_in[8], (const float*)d_in[10], (const float*)d_in[12], (const float*)d_in[16],
        (const float*)d_in[3], (const float*)d_in[5], (const float*)d_in[7], (const float*)d_in[15],
        (const float*)d_in[9], (const float*)d_in[11], (const float*)d_in[13], (const float*)d_in[17],
        Wcat, bias_cat);

    const int gpc = (N_C + 127) / 128, gpp = (N_P + 127) / 128;

    // ---- phase A: compound->protein ----
    // cq = comp @ Wq_c^T (+b) ; [pk|pv] = prot @ [Wk_p;Wv_p]^T fused N=512
    mfma_gemm<0><<<dim3(gpc, 2, 1), 256, 0, stream>>>(comp_bf, Wcat, tabA, bias_cat,
        nullptr, nullptr, nullptr, nullptr, N_C, 256, 256, 256);
    mfma_gemm<0><<<dim3(gpp, 4, 1), 256, 0, stream>>>(prot_bf, Wcat + 5 * 65536, tabKV, bias_cat + 1280,
        nullptr, nullptr, nullptr, nullptr, N_P, 512, 256, 256);

    mfma_gemm<1><<<dim3(1, 2, NB), 256, 0, stream>>>(tabA, tabKV, S, nullptr,
        comp_idx, prot_idx, comp_lens, prot_lens, MC, MP, 256, 512);
    softmax_bf16<MP><<<dim3((NB * MC) / 4), 256, 0, stream>>>(S, imp_c, NB * MC);
    imp_p_max<<<dim3(NB), 256, 0, stream>>>(S, comp_lens, imp_p);
    mfma_gemm<2><<<dim3(1, 2, NB), 256, 0, stream>>>(S, tabKV + 256, cfused, nullptr,
        nullptr, prot_idx, nullptr, nullptr, MC, 256, MP, 512);
    mfma_gemm<3><<<dim3((NB * MC) / 64, 1, 1), 256, 0, stream>>>(cfused, Wcat + 3 * 65536, cfused, bias_cat + 768,
        nullptr, nullptr, nullptr, nullptr, NB * MC, 256, 256, 256);

    // ---- phase B: protein->compound ----
    mfma_gemm<0><<<dim3(gpp, 2, 1), 256, 0, stream>>>(prot_bf, Wcat + 4 * 65536, tabA, bias_cat + 1024,
        nullptr, nullptr, nullptr, nullptr, N_P, 256, 256, 256);
    mfma_gemm<0><<<dim3(gpc, 4, 1), 256, 0, stream>>>(comp_bf, Wcat + 1 * 65536, tabKV, bias_cat + 256,
        nullptr, nullptr, nullptr, nullptr, N_C, 512, 256, 256);

    mfma_gemm<1><<<dim3(2, 1, NB), 256, 0, stream>>>(tabA, tabKV, S, nullptr,
        prot_idx, comp_idx, prot_lens, comp_lens, MP, MC, 256, 512);
    softmax_bf16<MC><<<dim3((NB * MP) / 4), 256, 0, stream>>>(S, nullptr, NB * MP);
    mfma_gemm<2><<<dim3(2, 2, NB), 256, 0, stream>>>(S, tabKV + 256, pfused, nullptr,
        nullptr, comp_idx, nullptr, nullptr, MP, 256, MC, 512);
    mfma_gemm<3><<<dim3((NB * MP) / 64, 1, 1), 256, 0, stream>>>(pfused, Wcat + 7 * 65536, pfused, bias_cat + 1792,
        nullptr, nullptr, nullptr, nullptr, NB * MP, 256, 256, 256);

    // ---- pooling + logit ----
    pool_kernel<<<dim3(NB), 256, 0, stream>>>(cfused, pfused, imp_c, imp_p, comp_lens, prot_lens, out);
}

// Round 5
// 200.280 us; speedup vs baseline: 1.6383x; 1.3277x over previous
//
#include <hip/hip_runtime.h>
#include <cstdint>

typedef __attribute__((ext_vector_type(8))) short short8;
typedef __attribute__((ext_vector_type(8))) unsigned short ushort8;
typedef __attribute__((ext_vector_type(4))) unsigned short ushort4v;
typedef __attribute__((ext_vector_type(4))) float f32x4;

constexpr int NB = 256, MC = 128, MP = 256;
constexpr float L2E = 1.442695041f;

__device__ __forceinline__ float b2f(unsigned short h) { return __uint_as_float(((unsigned)h) << 16); }
__device__ __forceinline__ unsigned short f2b(float f) {
    unsigned u = __float_as_uint(f);
    u += 0x7fffu + ((u >> 16) & 1u);
    return (unsigned short)(u >> 16);
}
__device__ __forceinline__ float sigmoid_f(float x) {
    return __builtin_amdgcn_rcpf(1.f + exp2f(-L2E * x));
}
__device__ __forceinline__ void gld_lds16(const unsigned short* g, unsigned short* l) {
    __builtin_amdgcn_global_load_lds((const __attribute__((address_space(1))) void*)g,
                                     (__attribute__((address_space(3))) void*)l, 16, 0, 0);
}

__global__ __launch_bounds__(256)
void cvt_f32_bf16(const float* __restrict__ in, unsigned short* __restrict__ out, int n4) {
    int i = blockIdx.x * 256 + threadIdx.x;
    int stride = gridDim.x * 256;
    for (; i < n4; i += stride) {
        float4 v = ((const float4*)in)[i];
        ushort4v o;
        o.x = f2b(v.x); o.y = f2b(v.y); o.z = f2b(v.z); o.w = f2b(v.w);
        ((ushort4v*)out)[i] = o;
    }
}

// 8 weights -> Wcat [2048][256] bf16 + bias_cat[2048] f32.
// Row-block order: q_c,k_c,v_c,g_c,q_p,k_p,v_p,g_p (qkv contiguous per side).
__global__ __launch_bounds__(256)
void cvt_weights8(const float* w0, const float* w1, const float* w2, const float* w3,
                  const float* w4, const float* w5, const float* w6, const float* w7,
                  const float* b0, const float* b1, const float* b2, const float* b3,
                  const float* b4, const float* b5, const float* b6, const float* b7,
                  unsigned short* __restrict__ Wcat, float* __restrict__ bias_cat)
{
    const float* wsel[8] = {w0, w1, w2, w3, w4, w5, w6, w7};
    const float* bsel[8] = {b0, b1, b2, b3, b4, b5, b6, b7};
    int j = blockIdx.y;
    int i = blockIdx.x * 256 + threadIdx.x;
    float4 v = ((const float4*)wsel[j])[i];
    ushort4v o;
    o.x = f2b(v.x); o.y = f2b(v.y); o.z = f2b(v.z); o.w = f2b(v.w);
    ((ushort4v*)(Wcat + (size_t)j * 65536))[i] = o;
    if (blockIdx.x == 0) bias_cat[j * 256 + threadIdx.x] = bsel[j][threadIdx.x];
}

// ---------------------------------------------------------------------------
// bf16 MFMA GEMM, double-buffered BK=32 (2-phase pipeline).
// LDS: elem (row r,k) at short-index r*32 + ((k>>3 ^ (r&3))<<3) + (k&7);
// staged linearly from inverse-swizzled GLOBAL source (rule #21).
// MODE 0 proj : Y[gr,gc] = dot + bias[gc], C stride N (N=768 fused qkv)
// MODE 2 AV   : O = Attn . V[gather]  (V rows via bidx, stride bstr, +off)
// MODE 3 gate : C = C * sigmoid(dot + bias), in place (block owns full rows)
// ---------------------------------------------------------------------------
template<int MODE>
__global__ __launch_bounds__(256, 4)
void mfma_gemm(const unsigned short* __restrict__ A, const unsigned short* __restrict__ B,
               unsigned short* __restrict__ C, const float* __restrict__ bias,
               const int* __restrict__ aidx, const int* __restrict__ bidx,
               int M, int N, int K, int bstr)
{
    constexpr int BM = (MODE == 3) ? 64 : 128;
    constexpr int BN = (MODE == 3) ? 256 : 128;
    __shared__ __align__(16) unsigned short As[2][BM * 32];
    __shared__ __align__(16) unsigned short Bs[2][BN * 32];

    const int t = threadIdx.x;
    const int wid = t >> 6, l = t & 63, g = l >> 4, lr = l & 15;
    const int wrb = (MODE == 3) ? 0 : (wid >> 1) * 64;
    const int wcb = (MODE == 3) ? wid * 64 : (wid & 1) * 64;
    const int r0 = blockIdx.x * BM, c0 = blockIdx.y * BN;
    const int bz = blockIdx.z;

    f32x4 acc[4][4];
#pragma unroll
    for (int mi = 0; mi < 4; ++mi)
#pragma unroll
        for (int ni = 0; ni < 4; ++ni) acc[mi][ni] = (f32x4){0.f, 0.f, 0.f, 0.f};

    auto stage = [&](int buf, int k0) {
        constexpr int CA = (BM * 4) / 256;
#pragma unroll
        for (int p = 0; p < CA; ++p) {
            int i = p * 256 + t;
            int r = i >> 2, s = i & 3;
            const unsigned short* ap;
            if constexpr (MODE == 0) { int gr = r0 + r; if (gr >= M) gr = M - 1; ap = A + (size_t)gr * 256; }
            else if constexpr (MODE == 2) { ap = A + ((size_t)bz * M + r0 + r) * K; }
            else { ap = A + (size_t)(r0 + r) * 256; }
            gld_lds16(ap + k0 + ((s ^ (r & 3)) << 3), &As[buf][i * 8]);
        }
        if constexpr (MODE == 2) {
            // gather 32 V rows, transpose into Bs[c][k] as packed k-pairs
            int a = t & 15, cb = (t >> 4) * 8;
            const unsigned short* q0 = B + (size_t)bidx[bz * K + k0 + 2 * a] * bstr + c0 + cb;
            const unsigned short* q1 = B + (size_t)bidx[bz * K + k0 + 2 * a + 1] * bstr + c0 + cb;
            ushort8 v0 = *(const ushort8*)q0;
            ushort8 v1 = *(const ushort8*)q1;
            int gg = a >> 2, kl = (2 * a) & 7;
#pragma unroll
            for (int e = 0; e < 8; ++e) {
                int c = cb + e;
                *(unsigned*)&Bs[buf][c * 32 + ((gg ^ (c & 3)) << 3) + kl] =
                    (unsigned)(unsigned short)v0[e] | ((unsigned)(unsigned short)v1[e] << 16);
            }
        } else {
            constexpr int CB = (BN * 4) / 256;
#pragma unroll
            for (int p = 0; p < CB; ++p) {
                int i = p * 256 + t;
                int c = i >> 2, s = i & 3;
                const unsigned short* bp = B + (size_t)(c0 + c) * bstr;
                gld_lds16(bp + k0 + ((s ^ (c & 3)) << 3), &Bs[buf][i * 8]);
            }
        }
    };

    stage(0, 0);
    __syncthreads();
    const int NT_ = K >> 5;
    for (int it = 0; it < NT_; ++it) {
        const int cur = it & 1;
        if (it + 1 < NT_) stage(cur ^ 1, (it + 1) << 5);
        short8 af[4], bfr[4];
#pragma unroll
        for (int mi = 0; mi < 4; ++mi) {
            int r = wrb + mi * 16 + lr;
            af[mi] = *(const short8*)&As[cur][r * 32 + ((g ^ (r & 3)) << 3)];
        }
#pragma unroll
        for (int ni = 0; ni < 4; ++ni) {
            int c = wcb + ni * 16 + lr;
            bfr[ni] = *(const short8*)&Bs[cur][c * 32 + ((g ^ (c & 3)) << 3)];
        }
#pragma unroll
        for (int mi = 0; mi < 4; ++mi)
#pragma unroll
            for (int ni = 0; ni < 4; ++ni)
                acc[mi][ni] = __builtin_amdgcn_mfma_f32_16x16x32_bf16(af[mi], bfr[ni], acc[mi][ni], 0, 0, 0);
        if (it + 1 < NT_) __syncthreads();
    }

#pragma unroll
    for (int mi = 0; mi < 4; ++mi) {
#pragma unroll
        for (int ni = 0; ni < 4; ++ni) {
#pragma unroll
            for (int q = 0; q < 4; ++q) {
                int gr = r0 + wrb + mi * 16 + g * 4 + q;
                int gc = c0 + wcb + ni * 16 + lr;
                float v = acc[mi][ni][q];
                if constexpr (MODE == 0) {
                    if (gr < M) C[(size_t)gr * N + gc] = f2b(v + bias[gc]);
                } else if constexpr (MODE == 2) {
                    C[((size_t)bz * M + gr) * 256 + gc] = f2b(v);
                } else {
                    size_t o = (size_t)gr * 256 + gc;
                    C[o] = f2b(b2f(C[o]) * sigmoid_f(v + bias[gc]));
                }
            }
        }
    }
}

// ---------------------------------------------------------------------------
// Fused masked-score + softmax + importance kernel. One block = one batch.
// 512 threads = 8 waves in WR x WC grid; wave computes a 64x64 S-tile in
// accumulators; full [M][N] per block. Row softmax: in-lane over ni, then
// shfl_xor across the 16-lane lr group, then LDS across WC waves. Writes
// normalized attn (bf16), imp_c = 1/rowsum (== row max over valid cols) and
// imp_p = column max over valid rows (IMP only).
// A rows = Q side (gathered aidx, stride 768), B rows = K side (gathered
// bidx, stride 768). Mask: row < rl && col < cl.
// ---------------------------------------------------------------------------
template<int M, int N, int WR, int WC, bool IMP>
__global__ __launch_bounds__(512, 2)
void attn_score(const unsigned short* __restrict__ Aq, const unsigned short* __restrict__ Bk,
                unsigned short* __restrict__ S,
                const int* __restrict__ aidx, const int* __restrict__ bidx,
                const int* __restrict__ rlen, const int* __restrict__ cln,
                float* __restrict__ imp_c, float* __restrict__ imp_p)
{
    __shared__ __align__(16) unsigned short As[2][M * 32];
    __shared__ __align__(16) unsigned short Bs[2][N * 32];
    __shared__ float redA[M][WC + 1];
    __shared__ float redB[IMP ? N : 1][IMP ? (WR + 1) : 1];

    const int t = threadIdx.x;
    const int wid = t >> 6, l = t & 63, g = l >> 4, lr = l & 15;
    const int wr = wid / WC, wc = wid % WC;
    const int R0 = wr * 64, C0 = wc * 64;
    const int bz = blockIdx.x;
    const int rl = rlen[bz], cl_ = cln[bz];

    f32x4 acc[4][4];
#pragma unroll
    for (int mi = 0; mi < 4; ++mi)
#pragma unroll
        for (int ni = 0; ni < 4; ++ni) acc[mi][ni] = (f32x4){0.f, 0.f, 0.f, 0.f};

    auto stage = [&](int buf, int k0) {
        constexpr int CA = (M * 4) / 512;
#pragma unroll
        for (int p = 0; p < CA; ++p) {
            int i = p * 512 + t;
            int r = i >> 2, s = i & 3;
            const unsigned short* ap = Aq + (size_t)aidx[bz * M + r] * 768;
            gld_lds16(ap + k0 + ((s ^ (r & 3)) << 3), &As[buf][i * 8]);
        }
        constexpr int CB = (N * 4) / 512;
#pragma unroll
        for (int p = 0; p < CB; ++p) {
            int i = p * 512 + t;
            int c = i >> 2, s = i & 3;
            const unsigned short* bp = Bk + (size_t)bidx[bz * N + c] * 768;
            gld_lds16(bp + k0 + ((s ^ (c & 3)) << 3), &Bs[buf][i * 8]);
        }
    };

    stage(0, 0);
    __syncthreads();
#pragma unroll 1
    for (int it = 0; it < 8; ++it) {
        const int cur = it & 1;
        if (it + 1 < 8) stage(cur ^ 1, (it + 1) << 5);
        short8 af[4], bfr[4];
#pragma unroll
        for (int mi = 0; mi < 4; ++mi) {
            int r = R0 + mi * 16 + lr;
            af[mi] = *(const short8*)&As[cur][r * 32 + ((g ^ (r & 3)) << 3)];
        }
#pragma unroll
        for (int ni = 0; ni < 4; ++ni) {
            int c = C0 + ni * 16 + lr;
            bfr[ni] = *(const short8*)&Bs[cur][c * 32 + ((g ^ (c & 3)) << 3)];
        }
#pragma unroll
        for (int mi = 0; mi < 4; ++mi)
#pragma unroll
            for (int ni = 0; ni < 4; ++ni)
                acc[mi][ni] = __builtin_amdgcn_mfma_f32_16x16x32_bf16(af[mi], bfr[ni], acc[mi][ni], 0, 0, 0);
        if (it + 1 < 8) __syncthreads();
    }

    // ---- mask + scale (scores stay f32) ----
#pragma unroll
    for (int mi = 0; mi < 4; ++mi)
#pragma unroll
        for (int ni = 0; ni < 4; ++ni)
#pragma unroll
            for (int q = 0; q < 4; ++q) {
                int row = R0 + mi * 16 + g * 4 + q;
                int col = C0 + ni * 16 + lr;
                acc[mi][ni][q] = (row < rl && col < cl_) ? acc[mi][ni][q] * 0.0625f : -1e9f;
            }

    // ---- row max: in-lane over ni, shfl over lr group, LDS over WC ----
    float rm[4][4];
#pragma unroll
    for (int mi = 0; mi < 4; ++mi)
#pragma unroll
        for (int q = 0; q < 4; ++q) {
            float m = fmaxf(fmaxf(acc[mi][0][q], acc[mi][1][q]), fmaxf(acc[mi][2][q], acc[mi][3][q]));
#pragma unroll
            for (int o = 1; o < 16; o <<= 1) m = fmaxf(m, __shfl_xor(m, o));
            rm[mi][q] = m;
        }
    if (lr == 0)
#pragma unroll
        for (int mi = 0; mi < 4; ++mi)
#pragma unroll
            for (int q = 0; q < 4; ++q)
                redA[R0 + mi * 16 + g * 4 + q][wc] = rm[mi][q];
    __syncthreads();
    float Mrow[4][4];
#pragma unroll
    for (int mi = 0; mi < 4; ++mi)
#pragma unroll
        for (int q = 0; q < 4; ++q) {
            int row = R0 + mi * 16 + g * 4 + q;
            float m = redA[row][0];
#pragma unroll
            for (int w = 1; w < WC; ++w) m = fmaxf(m, redA[row][w]);
            Mrow[mi][q] = m;
        }
    __syncthreads();

    // ---- exp + row sum ----
#pragma unroll
    for (int mi = 0; mi < 4; ++mi)
#pragma unroll
        for (int q = 0; q < 4; ++q) {
            float s = 0.f;
#pragma unroll
            for (int ni = 0; ni < 4; ++ni) {
                float e = exp2f((acc[mi][ni][q] - Mrow[mi][q]) * L2E);
                acc[mi][ni][q] = e;
                s += e;
            }
#pragma unroll
            for (int o = 1; o < 16; o <<= 1) s += __shfl_xor(s, o);
            rm[mi][q] = s;   // reuse rm as rowsum
        }
    if (lr == 0)
#pragma unroll
        for (int mi = 0; mi < 4; ++mi)
#pragma unroll
            for (int q = 0; q < 4; ++q)
                redA[R0 + mi * 16 + g * 4 + q][wc] = rm[mi][q];
    __syncthreads();
    float inv[4][4];
#pragma unroll
    for (int mi = 0; mi < 4; ++mi)
#pragma unroll
        for (int q = 0; q < 4; ++q) {
            int row = R0 + mi * 16 + g * 4 + q;
            float s = redA[row][0];
#pragma unroll
            for (int w = 1; w < WC; ++w) s += redA[row][w];
            inv[mi][q] = 1.f / s;
        }

    // ---- write normalized attn (bf16) ----
#pragma unroll
    for (int mi = 0; mi < 4; ++mi)
#pragma unroll
        for (int ni = 0; ni < 4; ++ni)
#pragma unroll
            for (int q = 0; q < 4; ++q) {
                int row = R0 + mi * 16 + g * 4 + q;
                int col = C0 + ni * 16 + lr;
                S[((size_t)bz * M + row) * N + col] = f2b(acc[mi][ni][q] * inv[mi][q]);
            }

    if constexpr (IMP) {
        // imp_c[row] = 1/rowsum (== max over valid cols of softmaxed row)
        if (wc == 0 && lr == 0)
#pragma unroll
            for (int mi = 0; mi < 4; ++mi)
#pragma unroll
                for (int q = 0; q < 4; ++q)
                    imp_c[bz * M + R0 + mi * 16 + g * 4 + q] = inv[mi][q];
        // imp_p[col] = max over valid rows (< rl) of attn
        float cm[4];
#pragma unroll
        for (int ni = 0; ni < 4; ++ni) {
            float m = -1e30f;
#pragma unroll
            for (int mi = 0; mi < 4; ++mi)
#pragma unroll
                for (int q = 0; q < 4; ++q) {
                    int row = R0 + mi * 16 + g * 4 + q;
                    if (row < rl) m = fmaxf(m, acc[mi][ni][q] * inv[mi][q]);
                }
            m = fmaxf(m, __shfl_xor(m, 16));
            m = fmaxf(m, __shfl_xor(m, 32));
            cm[ni] = m;
        }
        if (g == 0)
#pragma unroll
            for (int ni = 0; ni < 4; ++ni)
                redB[C0 + ni * 16 + lr][wr] = cm[ni];
        __syncthreads();
        if (t < N) {
            float m = redB[t][0];
#pragma unroll
            for (int w = 1; w < WR; ++w) m = fmaxf(m, redB[t][w]);
            imp_p[bz * N + t] = m;
        }
    }
}

__device__ __forceinline__ float br_max(float v, float* red)
{
#pragma unroll
    for (int o = 32; o; o >>= 1) v = fmaxf(v, __shfl_xor(v, o));
    __syncthreads();
    if ((threadIdx.x & 63) == 0) red[threadIdx.x >> 6] = v;
    __syncthreads();
    return fmaxf(fmaxf(red[0], red[1]), fmaxf(red[2], red[3]));
}

__device__ __forceinline__ float br_sum(float v, float* red)
{
#pragma unroll
    for (int o = 32; o; o >>= 1) v += __shfl_xor(v, o);
    __syncthreads();
    if ((threadIdx.x & 63) == 0) red[threadIdx.x >> 6] = v;
    __syncthreads();
    return red[0] + red[1] + red[2] + red[3];
}

__global__ __launch_bounds__(256)
void pool_kernel(const unsigned short* __restrict__ cg, const unsigned short* __restrict__ pg,
                 const float* __restrict__ imp_c, const float* __restrict__ imp_p,
                 const int* __restrict__ clens, const int* __restrict__ plens,
                 float* __restrict__ out)
{
    int b = blockIdx.x, t = threadIdx.x;
    __shared__ float w[256];
    __shared__ float red[4];
    int cl = clens[b], pl = plens[b];

    float x = (t < 128 && t < cl) ? imp_c[b * MC + t] : -1e30f;
    float mx = br_max(x, red);
    float e = (t < 128) ? exp2f((x - mx) * L2E) : 0.f;
    float s = br_sum(e, red);
    if (t < 128) w[t] = e / s;
    __syncthreads();

    float hv = 0.f;
    for (int n = 0; n < MC; ++n)
        hv += w[n] * b2f(cg[((size_t)b * MC + n) * 256 + t]);
    __syncthreads();

    float x2 = (t < pl) ? imp_p[b * MP + t] : -1e30f;
    float mx2 = br_max(x2, red);
    float e2 = exp2f((x2 - mx2) * L2E);
    float s2 = br_sum(e2, red);
    w[t] = e2 / s2;
    __syncthreads();

    float dv = 0.f;
    for (int m = 0; m < MP; ++m)
        dv += w[m] * b2f(pg[((size_t)b * MP + m) * 256 + t]);

    float logit = br_sum(hv * dv, red);
    if (t == 0) out[b] = 1.f / (1.f + expf(-logit));
}

// ---------------------------------------------------------------------------
extern "C" void kernel_launch(void* const* d_in, const int* in_sizes, int n_in,
                              void* d_out, int out_size, void* d_ws, size_t ws_size,
                              hipStream_t stream)
{
    const float* comp_emb = (const float*)d_in[0];
    const float* prot_emb = (const float*)d_in[1];
    const int* comp_idx  = (const int*)d_in[18];
    const int* prot_idx  = (const int*)d_in[19];
    const int* comp_lens = (const int*)d_in[20];
    const int* prot_lens = (const int*)d_in[21];
    float* out = (float*)d_out;

    const int N_C = in_sizes[0] / 256;
    const int N_P = in_sizes[1] / 256;
    const size_t NTc = (size_t)N_C * 256;
    const size_t NTp = (size_t)N_P * 256;

    // ---- workspace layout (bf16 elems), ~168 MB of the 256 MiB ws ----
    unsigned short* comp_bf = (unsigned short*)d_ws;
    unsigned short* prot_bf = comp_bf + NTc;
    unsigned short* Wcat    = prot_bf + NTp;                 // [2048][256]
    float* bias_cat         = (float*)(Wcat + 2048 * 256);   // [2048]
    unsigned short* tabC    = (unsigned short*)(bias_cat + 2048);  // [N_C][768] q|k|v
    unsigned short* tabP    = tabC + (size_t)N_C * 768;            // [N_P][768] q|k|v
    unsigned short* S_cp    = tabP + (size_t)N_P * 768;      // [NB][128][256]
    unsigned short* S_pc    = S_cp + (size_t)NB * MC * MP;   // [NB][256][128]
    unsigned short* cfused  = S_pc + (size_t)NB * MP * MC;   // [NB][128][256]
    unsigned short* pfused  = cfused + (size_t)NB * MC * 256; // [NB][256][256]
    float* imp_c = (float*)(pfused + (size_t)NB * MP * 256);
    float* imp_p = imp_c + NB * MC;

    // ---- conversions ----
    cvt_f32_bf16<<<dim3(2048), 256, 0, stream>>>(comp_emb, comp_bf, (int)(NTc / 4));
    cvt_f32_bf16<<<dim3(2048), 256, 0, stream>>>(prot_emb, prot_bf, (int)(NTp / 4));
    cvt_weights8<<<dim3(64, 8), 256, 0, stream>>>(
        (const float*)d_in[2], (const float*)d_in[4], (const float*)d_in[6], (const float*)d_in[14],
        (const float*)d_in[8], (const float*)d_in[10], (const float*)d_in[12], (const float*)d_in[16],
        (const float*)d_in[3], (const float*)d_in[5], (const float*)d_in[7], (const float*)d_in[15],
        (const float*)d_in[9], (const float*)d_in[11], (const float*)d_in[13], (const float*)d_in[17],
        Wcat, bias_cat);

    const int gpc = (N_C + 127) / 128, gpp = (N_P + 127) / 128;

    // ---- fused qkv projections (one per side) ----
    mfma_gemm<0><<<dim3(gpc, 6, 1), 256, 0, stream>>>(comp_bf, Wcat, tabC, bias_cat,
        nullptr, nullptr, N_C, 768, 256, 256);
    mfma_gemm<0><<<dim3(gpp, 6, 1), 256, 0, stream>>>(prot_bf, Wcat + 1024 * 256, tabP, bias_cat + 1024,
        nullptr, nullptr, N_P, 768, 256, 256);

    // ---- fused score+softmax+imp, both directions ----
    attn_score<128, 256, 2, 4, true><<<dim3(NB), 512, 0, stream>>>(
        tabC, tabP + 256, S_cp, comp_idx, prot_idx, comp_lens, prot_lens, imp_c, imp_p);
    attn_score<256, 128, 4, 2, false><<<dim3(NB), 512, 0, stream>>>(
        tabP, tabC + 256, S_pc, prot_idx, comp_idx, prot_lens, comp_lens, nullptr, nullptr);

    // ---- attn @ V ----
    mfma_gemm<2><<<dim3(1, 2, NB), 256, 0, stream>>>(S_cp, tabP + 512, cfused, nullptr,
        nullptr, prot_idx, MC, 256, MP, 768);
    mfma_gemm<2><<<dim3(2, 2, NB), 256, 0, stream>>>(S_pc, tabC + 512, pfused, nullptr,
        nullptr, comp_idx, MP, 256, MC, 768);

    // ---- sigmoid gating (in place) ----
    mfma_gemm<3><<<dim3((NB * MC) / 64, 1, 1), 256, 0, stream>>>(cfused, Wcat + 768 * 256, cfused, bias_cat + 768,
        nullptr, nullptr, NB * MC, 256, 256, 256);
    mfma_gemm<3><<<dim3((NB * MP) / 64, 1, 1), 256, 0, stream>>>(pfused, Wcat + 1792 * 256, pfused, bias_cat + 1792,
        nullptr, nullptr, NB * MP, 256, 256, 256);

    // ---- pooling + logit ----
    pool_kernel<<<dim3(NB), 256, 0, stream>>>(cfused, pfused, imp_c, imp_p, comp_lens, prot_lens, out);
}